// Round 1
// baseline (131.129 us; speedup 1.0000x reference)
//
#include <hip/hip_runtime.h>
#include <hip/hip_bf16.h>

#define BATCH 16
#define SEQ   4096
#define DIM   64
#define WIN   512

constexpr int BM = 64;   // q rows per block
constexpr int BN = 64;   // keys per tile
constexpr int PAD = 8;   // LDS pad (bf16 elems) to break 128B-stride conflicts
// fold softmax scale and log2(e) into Q so p = exp2(s - m)
constexpr float QSCALE = 0.125f * 1.44269504088896340736f;

typedef __bf16 bf16x8 __attribute__((ext_vector_type(8)));
typedef float  f32x4  __attribute__((ext_vector_type(4)));

__global__ __launch_bounds__(256)
void swa_fa_kernel(const float* __restrict__ qg, const float* __restrict__ kg,
                   const float* __restrict__ vg, float* __restrict__ outg) {
    __shared__ __bf16 Qsh[BM][DIM + PAD];      // [qrow][d]
    __shared__ __bf16 Ksh[BN][DIM + PAD];      // [key][d]
    __shared__ __bf16 Vsh[DIM][BN + PAD];      // [d][key]  (transposed)
    __shared__ __bf16 Psh[4][16][BN + PAD];    // per-wave P buffer [row][key]

    const int tid  = threadIdx.x;
    const int lane = tid & 63;
    const int wave = tid >> 6;
    const int lr   = lane & 15;   // low 4 bits
    const int quad = lane >> 4;   // 0..3

    const int b     = blockIdx.y;
    const int qblk  = blockIdx.x;
    const int qrow0 = qblk * BM;

    const float* qb = qg + (size_t)b * SEQ * DIM;
    const float* kb = kg + (size_t)b * SEQ * DIM;
    const float* vb = vg + (size_t)b * SEQ * DIM;

    // ---- stage Q (scaled) fp32 -> bf16 ----
    #pragma unroll
    for (int i = 0; i < 4; ++i) {
        const int fid = tid + 256 * i;       // 0..1023 float4 slots
        const int row = fid >> 4;            // 64 rows
        const int c4  = (fid & 15) * 4;      // dim offset
        const float4 qv = *(const float4*)&qb[(size_t)(qrow0 + row) * DIM + c4];
        Qsh[row][c4 + 0] = (__bf16)(qv.x * QSCALE);
        Qsh[row][c4 + 1] = (__bf16)(qv.y * QSCALE);
        Qsh[row][c4 + 2] = (__bf16)(qv.z * QSCALE);
        Qsh[row][c4 + 3] = (__bf16)(qv.w * QSCALE);
    }
    __syncthreads();

    // Q A-frags for this wave: A[m=lr][k=quad*8+j], two k-steps of 32
    const bf16x8 qa0 = *(const bf16x8*)&Qsh[wave * 16 + lr][quad * 8];
    const bf16x8 qa1 = *(const bf16x8*)&Qsh[wave * 16 + lr][32 + quad * 8];

    const int wr0      = qrow0 + wave * 16;   // wave's first q row
    const int row_base = wr0 + quad * 4;      // this lane's first C-row

    f32x4 o[4];
    #pragma unroll
    for (int n = 0; n < 4; ++n) o[n] = (f32x4){0.f, 0.f, 0.f, 0.f};
    float m_run[4], l_run[4];
    #pragma unroll
    for (int r = 0; r < 4; ++r) { m_run[r] = -1e30f; l_run[r] = 0.f; }

    const int t0 = (qrow0 - (WIN - 1)) > 0 ? (qrow0 - (WIN - 1)) >> 6 : 0;
    const int t1 = qblk;

    for (int t = t0; t <= t1; ++t) {
        __syncthreads();   // previous tile fully consumed before overwrite
        // ---- stage K,V tile t ----
        #pragma unroll
        for (int i = 0; i < 4; ++i) {
            const int fid = tid + 256 * i;
            const int row = fid >> 4;           // key within tile
            const int c4  = (fid & 15) * 4;     // dim
            const size_t goff = (size_t)(t * BN + row) * DIM + c4;
            const float4 kv = *(const float4*)&kb[goff];
            Ksh[row][c4 + 0] = (__bf16)kv.x;
            Ksh[row][c4 + 1] = (__bf16)kv.y;
            Ksh[row][c4 + 2] = (__bf16)kv.z;
            Ksh[row][c4 + 3] = (__bf16)kv.w;
            const float4 vv = *(const float4*)&vb[goff];
            Vsh[c4 + 0][row] = (__bf16)vv.x;
            Vsh[c4 + 1][row] = (__bf16)vv.y;
            Vsh[c4 + 2][row] = (__bf16)vv.z;
            Vsh[c4 + 3][row] = (__bf16)vv.w;
        }
        __syncthreads();

        // wave-level skip: tile entirely older than this wave's window
        if (t * BN + (BN - 1) + (WIN - 1) < wr0) continue;

        // ---- QK^T : 4 n-tiles x 2 k-steps ----
        f32x4 sc[4];
        #pragma unroll
        for (int n = 0; n < 4; ++n) {
            const bf16x8 kf0 = *(const bf16x8*)&Ksh[n * 16 + lr][quad * 8];
            const bf16x8 kf1 = *(const bf16x8*)&Ksh[n * 16 + lr][32 + quad * 8];
            f32x4 s = (f32x4){0.f, 0.f, 0.f, 0.f};
            s = __builtin_amdgcn_mfma_f32_16x16x32_bf16(qa0, kf0, s, 0, 0, 0);
            s = __builtin_amdgcn_mfma_f32_16x16x32_bf16(qa1, kf1, s, 0, 0, 0);
            sc[n] = s;
        }

        // ---- mask + tile row-max ----
        float mt[4];
        #pragma unroll
        for (int r = 0; r < 4; ++r) mt[r] = -1e30f;
        #pragma unroll
        for (int n = 0; n < 4; ++n) {
            const int key = t * BN + n * 16 + lr;
            #pragma unroll
            for (int r = 0; r < 4; ++r) {
                const int row = row_base + r;
                const float sv = ((unsigned)(row - key) < (unsigned)WIN) ? sc[n][r] : -1e30f;
                sc[n][r] = sv;
                mt[r] = fmaxf(mt[r], sv);
            }
        }
        // reduce max across the 16 lanes holding this row group
        #pragma unroll
        for (int off = 1; off < 16; off <<= 1) {
            #pragma unroll
            for (int r = 0; r < 4; ++r)
                mt[r] = fmaxf(mt[r], __shfl_xor(mt[r], off));
        }
        float al[4];
        #pragma unroll
        for (int r = 0; r < 4; ++r) {
            const float mn = fmaxf(m_run[r], mt[r]);
            al[r] = exp2f(m_run[r] - mn);
            m_run[r] = mn;
            l_run[r] *= al[r];
        }
        // ---- p = exp2(s - m), accumulate partial l, spill P to LDS ----
        #pragma unroll
        for (int n = 0; n < 4; ++n) {
            #pragma unroll
            for (int r = 0; r < 4; ++r) {
                const float p = exp2f(sc[n][r] - m_run[r]);
                l_run[r] += p;
                Psh[wave][quad * 4 + r][n * 16 + lr] = (__bf16)p;
            }
        }
        // rescale o by alpha
        #pragma unroll
        for (int n = 0; n < 4; ++n) {
            #pragma unroll
            for (int r = 0; r < 4; ++r) o[n][r] *= al[r];
        }
        // ---- P back in A-layout, PV ----
        const bf16x8 pa0 = *(const bf16x8*)&Psh[wave][lr][quad * 8];
        const bf16x8 pa1 = *(const bf16x8*)&Psh[wave][lr][32 + quad * 8];
        #pragma unroll
        for (int n = 0; n < 4; ++n) {
            const bf16x8 vf0 = *(const bf16x8*)&Vsh[n * 16 + lr][quad * 8];
            const bf16x8 vf1 = *(const bf16x8*)&Vsh[n * 16 + lr][32 + quad * 8];
            o[n] = __builtin_amdgcn_mfma_f32_16x16x32_bf16(pa0, vf0, o[n], 0, 0, 0);
            o[n] = __builtin_amdgcn_mfma_f32_16x16x32_bf16(pa1, vf1, o[n], 0, 0, 0);
        }
    }

    // ---- epilogue: reduce partial l across 16 lanes, normalize, store ----
    #pragma unroll
    for (int off = 1; off < 16; off <<= 1) {
        #pragma unroll
        for (int r = 0; r < 4; ++r)
            l_run[r] += __shfl_xor(l_run[r], off);
    }
    float* ob = outg + (size_t)b * SEQ * DIM;
    #pragma unroll
    for (int r = 0; r < 4; ++r) {
        const float inv = 1.0f / l_run[r];
        const int row = row_base + r;
        #pragma unroll
        for (int n = 0; n < 4; ++n) {
            ob[(size_t)row * DIM + n * 16 + lr] = o[n][r] * inv;
        }
    }
}

extern "C" void kernel_launch(void* const* d_in, const int* in_sizes, int n_in,
                              void* d_out, int out_size, void* d_ws, size_t ws_size,
                              hipStream_t stream) {
    (void)in_sizes; (void)n_in; (void)out_size; (void)d_ws; (void)ws_size;
    const float* q = (const float*)d_in[0];
    const float* k = (const float*)d_in[1];
    const float* v = (const float*)d_in[2];
    float* out = (float*)d_out;
    dim3 grid(SEQ / BM, BATCH);
    swa_fa_kernel<<<grid, dim3(256), 0, stream>>>(q, k, v, out);
}

// Round 3
// 129.229 us; speedup vs baseline: 1.0147x; 1.0147x over previous
//
#include <hip/hip_runtime.h>

#define BATCH 16
#define SEQ   4096
#define DIM   64
#define WIN   512

constexpr int BM = 64;        // q rows per block
constexpr int BN = 64;        // keys per tile
constexpr int KS = DIM + 8;   // Ksh row stride (f16): 144 B, 16B-aligned rows
constexpr int VS = BN + 4;    // Vsh row stride (f16): 136 B, 8B-aligned rows
constexpr int OS = DIM + 4;   // Osh row stride (f32)
// fold softmax scale and log2(e) into Q so p = exp2(s - m)
constexpr float QSCALE  = 0.125f * 1.44269504088896340736f;
constexpr float MASKVAL = -3.0e38f;   // << m_run init (-1e30) so masked lanes give p=0

typedef _Float16 f16x2 __attribute__((ext_vector_type(2)));
typedef _Float16 f16x4 __attribute__((ext_vector_type(4)));
typedef _Float16 f16x8 __attribute__((ext_vector_type(8)));
typedef float    f32x4 __attribute__((ext_vector_type(4)));

__device__ __forceinline__ f16x2 pk2(float a, float b) {
    return __builtin_bit_cast(f16x2, __builtin_amdgcn_cvt_pkrtz(a, b));
}

__global__ __launch_bounds__(256)
void swa_kernel(const float* __restrict__ qg, const float* __restrict__ kg,
                const float* __restrict__ vg, float* __restrict__ outg) {
    // Ksh [BN][KS] f16 (9216 B) | Vsh [DIM][VS] f16 (8704 B); Osh f32 [BM][OS] overlays all
    __shared__ __align__(16) char smem[(BN * KS + DIM * VS) * 2];
    _Float16* Ksh = (_Float16*)smem;
    _Float16* Vsh = (_Float16*)(smem + BN * KS * 2);
    float*    Osh = (float*)smem;

    const int tid  = threadIdx.x;
    const int lane = tid & 63;
    const int wave = tid >> 6;
    const int lr   = lane & 15;
    const int quad = lane >> 4;

    const int b     = blockIdx.y;
    const int qblk  = blockIdx.x;
    const int qrow0 = qblk * BM;
    const int wr0   = qrow0 + wave * 16;
    const int q     = wr0 + lr;          // this lane's q column (S^T layout)

    const float* qb = qg + (size_t)b * SEQ * DIM;
    const float* kb = kg + (size_t)b * SEQ * DIM;
    const float* vb = vg + (size_t)b * SEQ * DIM;
    float*       ob = outg + (size_t)b * SEQ * DIM;

    // ---- Q B-frags straight from global into registers (no LDS, no barrier) ----
    // B-frag (16x16x32): lane holds Q[q=lr][d = chunk*32 + quad*8 + j], j=0..7
    const float* qp = qb + (size_t)q * DIM + quad * 8;
    const float4 a0 = *(const float4*)(qp + 0);
    const float4 a1 = *(const float4*)(qp + 4);
    const float4 a2 = *(const float4*)(qp + 32);
    const float4 a3 = *(const float4*)(qp + 36);
    union { f16x8 v; f16x2 h[4]; } uq0, uq1;
    uq0.h[0] = pk2(a0.x * QSCALE, a0.y * QSCALE);
    uq0.h[1] = pk2(a0.z * QSCALE, a0.w * QSCALE);
    uq0.h[2] = pk2(a1.x * QSCALE, a1.y * QSCALE);
    uq0.h[3] = pk2(a1.z * QSCALE, a1.w * QSCALE);
    uq1.h[0] = pk2(a2.x * QSCALE, a2.y * QSCALE);
    uq1.h[1] = pk2(a2.z * QSCALE, a2.w * QSCALE);
    uq1.h[2] = pk2(a3.x * QSCALE, a3.y * QSCALE);
    uq1.h[3] = pk2(a3.z * QSCALE, a3.w * QSCALE);
    const f16x8 qf0 = uq0.v, qf1 = uq1.v;

    f32x4 o[4];
    #pragma unroll
    for (int mi = 0; mi < 4; ++mi) o[mi] = (f32x4){0.f, 0.f, 0.f, 0.f};
    float m_run = -1e30f, l_run = 0.f;

    const int t0 = (qrow0 > (WIN - 1)) ? (qrow0 - (WIN - 1)) >> 6 : 0;
    const int t1 = qblk;

    for (int t = t0; t <= t1; ++t) {
        __syncthreads();   // prev tile fully consumed
        // ---- stage K (row-major, packed b64) and V (transposed, scatter) ----
        #pragma unroll
        for (int i = 0; i < 4; ++i) {
            const int fid = tid + 256 * i;
            const int row = fid >> 4;            // key within tile
            const int c4  = (fid & 15) * 4;      // d offset
            const size_t g = (size_t)(t * BN + row) * DIM + c4;
            const float4 kv = *(const float4*)&kb[g];
            union { f16x4 v; f16x2 h[2]; } uk;
            uk.h[0] = pk2(kv.x, kv.y);
            uk.h[1] = pk2(kv.z, kv.w);
            *(f16x4*)&Ksh[row * KS + c4] = uk.v;
            const float4 vv = *(const float4*)&vb[g];
            Vsh[(c4 + 0) * VS + row] = (_Float16)vv.x;
            Vsh[(c4 + 1) * VS + row] = (_Float16)vv.y;
            Vsh[(c4 + 2) * VS + row] = (_Float16)vv.z;
            Vsh[(c4 + 3) * VS + row] = (_Float16)vv.w;
        }
        __syncthreads();

        // wave-level skip: tile entirely below this wave's window
        if (t * BN + (BN - 1) < wr0 - (WIN - 1)) continue;
        const int kbase = t * BN;

        // ---- S^T = K * Q^T : 4 key m-tiles x 2 k-chunks of 32 ----
        f32x4 sc[4];
        #pragma unroll
        for (int mt = 0; mt < 4; ++mt) {
            const f16x8 kf0 = *(const f16x8*)&Ksh[(mt * 16 + lr) * KS + quad * 8];
            const f16x8 kf1 = *(const f16x8*)&Ksh[(mt * 16 + lr) * KS + 32 + quad * 8];
            f32x4 s = (f32x4){0.f, 0.f, 0.f, 0.f};
            s = __builtin_amdgcn_mfma_f32_16x16x32_f16(kf0, qf0, s, 0, 0, 0);
            s = __builtin_amdgcn_mfma_f32_16x16x32_f16(kf1, qf1, s, 0, 0, 0);
            sc[mt] = s;
        }

        // ---- mask only on window-edge tiles (wave-uniform branch) ----
        const bool edge = (kbase < wr0 + 15 - (WIN - 1)) || (kbase + BN - 1 > wr0);
        if (edge) {
            #pragma unroll
            for (int mt = 0; mt < 4; ++mt) {
                #pragma unroll
                for (int r = 0; r < 4; ++r) {
                    const int key = kbase + mt * 16 + quad * 4 + r;
                    sc[mt][r] = ((unsigned)(q - key) < (unsigned)WIN) ? sc[mt][r] : MASKVAL;
                }
            }
        }

        // ---- online softmax (one q per lane) ----
        float mt_ = MASKVAL;
        #pragma unroll
        for (int mtile = 0; mtile < 4; ++mtile)
            #pragma unroll
            for (int r = 0; r < 4; ++r) mt_ = fmaxf(mt_, sc[mtile][r]);
        mt_ = fmaxf(mt_, __shfl_xor(mt_, 16));
        mt_ = fmaxf(mt_, __shfl_xor(mt_, 32));
        const float mn    = fmaxf(m_run, mt_);
        const float alpha = exp2f(m_run - mn);
        m_run = mn;

        f16x4 pb[4];
        float ls = 0.f;
        #pragma unroll
        for (int nt = 0; nt < 4; ++nt) {
            const float p0 = exp2f(sc[nt][0] - mn);
            const float p1 = exp2f(sc[nt][1] - mn);
            const float p2 = exp2f(sc[nt][2] - mn);
            const float p3 = exp2f(sc[nt][3] - mn);
            ls += (p0 + p1) + (p2 + p3);
            union { f16x4 v; f16x2 h[2]; } up;
            up.h[0] = pk2(p0, p1);
            up.h[1] = pk2(p2, p3);
            pb[nt] = up.v;
        }
        l_run = l_run * alpha + ls;
        #pragma unroll
        for (int mi = 0; mi < 4; ++mi) o[mi] = o[mi] * alpha;

        // ---- O^T += V^T * P^T : P^T (C-layout) feeds B-operand of 16x16x16 directly ----
        #pragma unroll
        for (int nt = 0; nt < 4; ++nt) {
            #pragma unroll
            for (int mi = 0; mi < 4; ++mi) {
                const f16x4 vf = *(const f16x4*)&Vsh[(mi * 16 + lr) * VS + nt * 16 + quad * 4];
                o[mi] = __builtin_amdgcn_mfma_f32_16x16x16f16(vf, pb[nt], o[mi], 0, 0, 0);
            }
        }
    }

    // ---- epilogue: l reduce across quads, normalize, transpose via LDS, store ----
    l_run += __shfl_xor(l_run, 16);
    l_run += __shfl_xor(l_run, 32);
    const float inv = 1.0f / l_run;

    __syncthreads();   // all waves done with Ksh/Vsh before overlay
    float* Ow = Osh + wave * 16 * OS;   // per-wave private 16 x OS region
    #pragma unroll
    for (int mi = 0; mi < 4; ++mi) {
        float4 st;
        st.x = o[mi][0] * inv; st.y = o[mi][1] * inv;
        st.z = o[mi][2] * inv; st.w = o[mi][3] * inv;
        *(float4*)&Ow[lr * OS + mi * 16 + quad * 4] = st;
    }
    // read back coalesced (wave-private region; compiler orders via lgkmcnt)
    #pragma unroll
    for (int j = 0; j < 4; ++j) {
        const int qq = quad + 4 * j;
        const int d4 = lr * 4;
        const float4 vst = *(const float4*)&Ow[qq * OS + d4];
        *(float4*)&ob[(size_t)(wr0 + qq) * DIM + d4] = vst;
    }
}

extern "C" void kernel_launch(void* const* d_in, const int* in_sizes, int n_in,
                              void* d_out, int out_size, void* d_ws, size_t ws_size,
                              hipStream_t stream) {
    (void)in_sizes; (void)n_in; (void)out_size; (void)d_ws; (void)ws_size;
    const float* q = (const float*)d_in[0];
    const float* k = (const float*)d_in[1];
    const float* v = (const float*)d_in[2];
    float* out = (float*)d_out;
    dim3 grid(SEQ / BM, BATCH);
    swa_kernel<<<grid, dim3(256), 0, stream>>>(q, k, v, out);
}

// Round 4
// 109.935 us; speedup vs baseline: 1.1928x; 1.1755x over previous
//
#include <hip/hip_runtime.h>

#define BATCH 16
#define SEQ   4096
#define DIM   64
#define WIN   512

constexpr int BM = 128;       // q rows per block
constexpr int BN = 64;        // keys per tile
constexpr int NTHREADS = 512; // 8 waves
constexpr int KS = DIM + 8;   // Ksh row stride (f16 elems)
constexpr int VS = BN + 4;    // Vsh row stride (f16 elems)
constexpr int OS = DIM + 4;   // Osh row stride (f32 elems)
// fold softmax scale and log2(e) into Q so p = exp2(s - m)
constexpr float QSCALE  = 0.125f * 1.44269504088896340736f;
constexpr float MASKVAL = -3.0e38f;   // << m_run init (-1e30) so masked lanes give p=0

typedef _Float16 f16x2 __attribute__((ext_vector_type(2)));
typedef _Float16 f16x4 __attribute__((ext_vector_type(4)));
typedef _Float16 f16x8 __attribute__((ext_vector_type(8)));
typedef float    f32x4 __attribute__((ext_vector_type(4)));

__device__ __forceinline__ f16x2 pk2(float a, float b) {
    return __builtin_bit_cast(f16x2, __builtin_amdgcn_cvt_pkrtz(a, b));
}

__device__ __forceinline__ void stage_kv(_Float16* __restrict__ Ksh, _Float16* __restrict__ Vsh,
                                         const float4& kv, const float4& vv,
                                         int row, int c4) {
    union { f16x4 v; f16x2 h[2]; } uk;
    uk.h[0] = pk2(kv.x, kv.y);
    uk.h[1] = pk2(kv.z, kv.w);
    *(f16x4*)&Ksh[row * KS + c4] = uk.v;
    Vsh[(c4 + 0) * VS + row] = (_Float16)vv.x;
    Vsh[(c4 + 1) * VS + row] = (_Float16)vv.y;
    Vsh[(c4 + 2) * VS + row] = (_Float16)vv.z;
    Vsh[(c4 + 3) * VS + row] = (_Float16)vv.w;
}

__global__ __launch_bounds__(NTHREADS)
void swa_kernel(const float* __restrict__ qg, const float* __restrict__ kg,
                const float* __restrict__ vg, float* __restrict__ outg) {
    // staging: Ksh [BN][KS] f16 (9216 B) | Vsh [DIM][VS] f16 (8704 B) = 17920 B
    // epilogue: Osh f32 [BM][OS] = 34816 B (overlays staging)
    __shared__ __align__(16) char smem[BM * OS * 4];
    _Float16* Ksh = (_Float16*)smem;
    _Float16* Vsh = (_Float16*)(smem + BN * KS * 2);
    float*    Osh = (float*)smem;

    const int tid  = threadIdx.x;
    const int lane = tid & 63;
    const int wave = tid >> 6;     // 0..7
    const int lr   = lane & 15;
    const int quad = lane >> 4;

    const int b     = blockIdx.y;
    const int qblk  = blockIdx.x;
    const int qrow0 = qblk * BM;
    const int wr0   = qrow0 + wave * 16;
    const int q     = wr0 + lr;          // this lane's q column (S^T layout)

    const float* qb = qg + (size_t)b * SEQ * DIM;
    const float* kb = kg + (size_t)b * SEQ * DIM;
    const float* vb = vg + (size_t)b * SEQ * DIM;
    float*       ob = outg + (size_t)b * SEQ * DIM;

    // staging thread->slot map (two 32-row halves per tile)
    const int row0 = tid >> 4;            // 0..31
    const int c4   = (tid & 15) * 4;      // 0..60

    // ---- Q B-frags straight from global into registers ----
    const float* qp = qb + (size_t)q * DIM + quad * 8;
    const float4 a0 = *(const float4*)(qp + 0);
    const float4 a1 = *(const float4*)(qp + 4);
    const float4 a2 = *(const float4*)(qp + 32);
    const float4 a3 = *(const float4*)(qp + 36);
    union { f16x8 v; f16x2 h[4]; } uq0, uq1;
    uq0.h[0] = pk2(a0.x * QSCALE, a0.y * QSCALE);
    uq0.h[1] = pk2(a0.z * QSCALE, a0.w * QSCALE);
    uq0.h[2] = pk2(a1.x * QSCALE, a1.y * QSCALE);
    uq0.h[3] = pk2(a1.z * QSCALE, a1.w * QSCALE);
    uq1.h[0] = pk2(a2.x * QSCALE, a2.y * QSCALE);
    uq1.h[1] = pk2(a2.z * QSCALE, a2.w * QSCALE);
    uq1.h[2] = pk2(a3.x * QSCALE, a3.y * QSCALE);
    uq1.h[3] = pk2(a3.z * QSCALE, a3.w * QSCALE);
    const f16x8 qf0 = uq0.v, qf1 = uq1.v;

    f32x4 o[4];
    #pragma unroll
    for (int mi = 0; mi < 4; ++mi) o[mi] = (f32x4){0.f, 0.f, 0.f, 0.f};
    float m_run = -1e30f, l_run = 0.f;

    const int t0 = (qrow0 > (WIN - 1)) ? (qrow0 - (WIN - 1)) >> 6 : 0;
    const int t1 = (qrow0 + BM - 1) >> 6;

    // ---- prologue: stage tile t0 directly ----
    {
        const size_t g0 = (size_t)(t0 * BN + row0) * DIM + c4;
        stage_kv(Ksh, Vsh, *(const float4*)&kb[g0], *(const float4*)&vb[g0], row0, c4);
        const size_t g1 = g0 + (size_t)32 * DIM;
        stage_kv(Ksh, Vsh, *(const float4*)&kb[g1], *(const float4*)&vb[g1], row0 + 32, c4);
    }
    __syncthreads();

    for (int t = t0; t <= t1; ++t) {
        const bool have_next = (t < t1);
        float4 kpre0, kpre1, vpre0, vpre1;
        if (have_next) {
            // issue next tile's global loads NOW; consumed after the raw barrier,
            // so they stay in flight across compute (no vmcnt(0) drain)
            const size_t g0 = (size_t)((t + 1) * BN + row0) * DIM + c4;
            kpre0 = *(const float4*)&kb[g0];
            vpre0 = *(const float4*)&vb[g0];
            const size_t g1 = g0 + (size_t)32 * DIM;
            kpre1 = *(const float4*)&kb[g1];
            vpre1 = *(const float4*)&vb[g1];
        }

        const int kbase = t * BN;
        // wave-level skip: no key of this tile is inside this wave's window
        const bool active = (kbase + BN - 1 >= wr0 - (WIN - 1)) && (kbase <= wr0 + 15);
        if (active) {
            // ---- S^T = K * Q^T : 4 key m-tiles x 2 k-chunks of 32 ----
            f32x4 sc[4];
            #pragma unroll
            for (int mt = 0; mt < 4; ++mt) {
                const f16x8 kf0 = *(const f16x8*)&Ksh[(mt * 16 + lr) * KS + quad * 8];
                const f16x8 kf1 = *(const f16x8*)&Ksh[(mt * 16 + lr) * KS + 32 + quad * 8];
                f32x4 s = (f32x4){0.f, 0.f, 0.f, 0.f};
                s = __builtin_amdgcn_mfma_f32_16x16x32_f16(kf0, qf0, s, 0, 0, 0);
                s = __builtin_amdgcn_mfma_f32_16x16x32_f16(kf1, qf1, s, 0, 0, 0);
                sc[mt] = s;
            }

            // ---- mask only on window-edge tiles (wave-uniform branch) ----
            const bool edge = (kbase < wr0 + 15 - (WIN - 1)) || (kbase + BN - 1 > wr0);
            if (edge) {
                #pragma unroll
                for (int mt = 0; mt < 4; ++mt) {
                    #pragma unroll
                    for (int r = 0; r < 4; ++r) {
                        const int key = kbase + mt * 16 + quad * 4 + r;
                        sc[mt][r] = ((unsigned)(q - key) < (unsigned)WIN) ? sc[mt][r] : MASKVAL;
                    }
                }
            }

            // ---- online softmax (one q per lane) ----
            float mt_ = MASKVAL;
            #pragma unroll
            for (int mtile = 0; mtile < 4; ++mtile)
                #pragma unroll
                for (int r = 0; r < 4; ++r) mt_ = fmaxf(mt_, sc[mtile][r]);
            mt_ = fmaxf(mt_, __shfl_xor(mt_, 16));
            mt_ = fmaxf(mt_, __shfl_xor(mt_, 32));
            const float mn    = fmaxf(m_run, mt_);
            const float alpha = exp2f(m_run - mn);
            m_run = mn;

            f16x4 pb[4];
            float ls = 0.f;
            #pragma unroll
            for (int nt = 0; nt < 4; ++nt) {
                const float p0 = exp2f(sc[nt][0] - mn);
                const float p1 = exp2f(sc[nt][1] - mn);
                const float p2 = exp2f(sc[nt][2] - mn);
                const float p3 = exp2f(sc[nt][3] - mn);
                ls += (p0 + p1) + (p2 + p3);
                union { f16x4 v; f16x2 h[2]; } up;
                up.h[0] = pk2(p0, p1);
                up.h[1] = pk2(p2, p3);
                pb[nt] = up.v;
            }
            l_run = l_run * alpha + ls;
            #pragma unroll
            for (int mi = 0; mi < 4; ++mi) o[mi] = o[mi] * alpha;

            // ---- O^T += V^T * P^T : P^T (C-layout) is the B-operand of 16x16x16 ----
            #pragma unroll
            for (int nt = 0; nt < 4; ++nt) {
                #pragma unroll
                for (int mi = 0; mi < 4; ++mi) {
                    const f16x4 vf = *(const f16x4*)&Vsh[(mi * 16 + lr) * VS + nt * 16 + quad * 4];
                    o[mi] = __builtin_amdgcn_mfma_f32_16x16x16f16(vf, pb[nt], o[mi], 0, 0, 0);
                }
            }
        }

        // raw barrier: LDS read results already consumed (lgkmcnt waits precede MFMA
        // use); prefetch global loads must NOT be drained here -> no __syncthreads
        __builtin_amdgcn_s_barrier();
        if (have_next) {
            stage_kv(Ksh, Vsh, kpre0, vpre0, row0, c4);
            stage_kv(Ksh, Vsh, kpre1, vpre1, row0 + 32, c4);
        }
        __syncthreads();   // ds_writes visible; prefetch already consumed, no extra drain
    }

    // ---- epilogue: l reduce across quads, normalize, transpose via LDS, store ----
    l_run += __shfl_xor(l_run, 16);
    l_run += __shfl_xor(l_run, 32);
    const float inv = 1.0f / l_run;

    float* Ow = Osh + wave * 16 * OS;   // per-wave private 16 x OS region
    #pragma unroll
    for (int mi = 0; mi < 4; ++mi) {
        float4 st;
        st.x = o[mi][0] * inv; st.y = o[mi][1] * inv;
        st.z = o[mi][2] * inv; st.w = o[mi][3] * inv;
        *(float4*)&Ow[lr * OS + mi * 16 + quad * 4] = st;
    }
    #pragma unroll
    for (int j = 0; j < 4; ++j) {
        const int qq = quad + 4 * j;
        const int d4 = lr * 4;
        const float4 vst = *(const float4*)&Ow[qq * OS + d4];
        *(float4*)&ob[(size_t)(wr0 + qq) * DIM + d4] = vst;
    }
}

extern "C" void kernel_launch(void* const* d_in, const int* in_sizes, int n_in,
                              void* d_out, int out_size, void* d_ws, size_t ws_size,
                              hipStream_t stream) {
    (void)in_sizes; (void)n_in; (void)out_size; (void)d_ws; (void)ws_size;
    const float* q = (const float*)d_in[0];
    const float* k = (const float*)d_in[1];
    const float* v = (const float*)d_in[2];
    float* out = (float*)d_out;
    dim3 grid(SEQ / BM, BATCH);
    swa_kernel<<<grid, dim3(NTHREADS), 0, stream>>>(q, k, v, out);
}